// Round 6
// baseline (1466.215 us; speedup 1.0000x reference)
//
#include <hip/hip_runtime.h>

#define D 128          // D_IN == D_OUT == 128
#define RPB 128        // rows per bucket (LDS y-tile: 128 x 128 fp32 = 64 KiB)
#define RPB_SHIFT 7
#define BUCKMAX 1024
#define TILE 8192      // edges per binning tile

typedef short bf16x8 __attribute__((ext_vector_type(8)));
typedef float f32x4 __attribute__((ext_vector_type(4)));

__device__ inline unsigned short f2bf(float f) {  // RNE float->bf16
    unsigned u = __float_as_uint(f);
    unsigned r = u + 0x7FFFu + ((u >> 16) & 1u);
    return (unsigned short)(r >> 16);
}

// ---------------------------------------------------------------------------
// fp32 -> bf16 cast, 4 elements/thread, grid-stride
// ---------------------------------------------------------------------------
__global__ __launch_bounds__(256) void cast_bf16(const float* __restrict__ src,
                                                 unsigned short* __restrict__ dst,
                                                 long long n4) {
    long long i = (long long)blockIdx.x * 256 + threadIdx.x;
    const long long stride = (long long)gridDim.x * 256;
    for (; i < n4; i += stride) {
        float4 v = reinterpret_cast<const float4*>(src)[i];
        ushort4 o;
        o.x = f2bf(v.x); o.y = f2bf(v.y); o.z = f2bf(v.z); o.w = f2bf(v.w);
        reinterpret_cast<ushort4*>(dst)[i] = o;
    }
}

// ---------------------------------------------------------------------------
// Pass 0: exact per-bucket edge counts (bucket = row >> RPB_SHIFT)
// ---------------------------------------------------------------------------
__global__ __launch_bounds__(1024) void bucket_hist(const int* __restrict__ rows,
                                                    int* __restrict__ bucketCnt,
                                                    int E, int NBUCK) {
    __shared__ int h[BUCKMAX];
    for (int i = threadIdx.x; i < NBUCK; i += 1024) h[i] = 0;
    __syncthreads();
    const int t0 = blockIdx.x * TILE;
    const int tend = min(t0 + TILE, E);
    for (int i = t0 + threadIdx.x; i < tend; i += 1024)
        atomicAdd(&h[rows[i] >> RPB_SHIFT], 1);
    __syncthreads();
    for (int i = threadIdx.x; i < NBUCK; i += 1024)
        if (h[i]) atomicAdd(&bucketCnt[i], h[i]);
}

// ---------------------------------------------------------------------------
// Exclusive scan over NBUCK (<=1024) bucket counts; zero cursors.
// Thread t owns indices [4t, 4t+4): local sum -> Hillis-Steele -> local prefix.
// ---------------------------------------------------------------------------
__global__ __launch_bounds__(256) void bucket_scan(const int* __restrict__ bucketCnt,
                                                   int* __restrict__ bucketBase,
                                                   int* __restrict__ bucketCur,
                                                   int NBUCK) {
    __shared__ int ts[256];
    const int tid = threadIdx.x;
    int v[4];
    int s = 0;
#pragma unroll
    for (int j = 0; j < 4; ++j) {
        int idx = tid * 4 + j;
        v[j] = (idx < NBUCK) ? bucketCnt[idx] : 0;
        s += v[j];
    }
    ts[tid] = s;
    __syncthreads();
    for (int ofs = 1; ofs < 256; ofs <<= 1) {
        int add = (tid >= ofs) ? ts[tid - ofs] : 0;
        __syncthreads();
        ts[tid] += add;
        __syncthreads();
    }
    int run = ts[tid] - s;  // exclusive base for this thread's 4 buckets
#pragma unroll
    for (int j = 0; j < 4; ++j) {
        int idx = tid * 4 + j;
        if (idx < NBUCK) {
            bucketBase[idx] = run;
            bucketCur[idx] = 0;
        }
        run += v[j];
    }
    if (tid == 255) bucketBase[NBUCK] = ts[255];  // == E
}

// ---------------------------------------------------------------------------
// Pass 1: bin edges into bucket-major PACKED pairs: (lrow<<25 | col, val).
// Per-tile LDS histogram, ONE global atomic reservation per (tile,bucket),
// then single-stream uint2 writes into the tile's private contiguous chunk.
// 1024 threads for occupancy (was the R5 bottleneck at 6.7% occ).
// ---------------------------------------------------------------------------
__global__ __launch_bounds__(1024) void binA(const int* __restrict__ rows,
                                             const int* __restrict__ cols,
                                             const float* __restrict__ vals,
                                             const int* __restrict__ bucketBase,
                                             int* __restrict__ bucketCur,
                                             uint2* __restrict__ pairs,
                                             int E, int NBUCK) {
    __shared__ int h[BUCKMAX];
    __shared__ int base[BUCKMAX];
    const int t0 = blockIdx.x * TILE;
    const int tend = min(t0 + TILE, E);
    for (int i = threadIdx.x; i < NBUCK; i += 1024) h[i] = 0;
    __syncthreads();
    for (int i = t0 + threadIdx.x; i < tend; i += 1024)
        atomicAdd(&h[rows[i] >> RPB_SHIFT], 1);
    __syncthreads();
    for (int i = threadIdx.x; i < NBUCK; i += 1024) {
        int c = h[i];
        base[i] = c ? bucketBase[i] + atomicAdd(&bucketCur[i], c) : 0;
        h[i] = 0;  // reuse as local cursor
    }
    __syncthreads();
    for (int i = t0 + threadIdx.x; i < tend; i += 1024) {
        int r = rows[i];
        int b = r >> RPB_SHIFT;
        int p = base[b] + atomicAdd(&h[b], 1);
        unsigned pk = ((unsigned)(r & (RPB - 1)) << 25) | (unsigned)cols[i];
        pairs[p] = make_uint2(pk, __float_as_uint(vals[i]));
    }
}

// ---------------------------------------------------------------------------
// Fused aggregation: one block per 128-row bucket. fp32 y-tile lives in LDS;
// edges processed unordered via LDS float atomics (ds_add_f32). Pairs
// batch-loaded 64/wave, shfl-broadcast in branch-free groups of 8 (8 gathers
// in flight). Pad lanes carry pk=0,v=0 -> add 0.0 to row 0 (harmless).
// Replaces csr_build + csr_gather (no sorted-pairs round-trip, no offsets).
// ---------------------------------------------------------------------------
__global__ __launch_bounds__(512) void bucket_spmm(
    const unsigned short* __restrict__ xb,
    const int* __restrict__ bucketBase,
    const uint2* __restrict__ pairs,
    unsigned short* __restrict__ yb, int N) {
    __shared__ float ylds[RPB][D];  // 64 KiB
    const int buck = blockIdx.x;
    const int row0 = buck * RPB;
    const int tid = threadIdx.x;

    // zero the tile
    float4 z = make_float4(0.f, 0.f, 0.f, 0.f);
    float4* yf4 = reinterpret_cast<float4*>(&ylds[0][0]);
    for (int i = tid; i < RPB * D / 4; i += 512) yf4[i] = z;
    __syncthreads();

    const int beg = bucketBase[buck], end = bucketBase[buck + 1];
    const int wave = tid >> 6, lane = tid & 63;

    for (int base = beg + wave * 64; base < end; base += 512) {
        const int rem = min(end - base, 64);  // wave-uniform
        uint2 e = make_uint2(0u, 0u);
        if (lane < rem) e = pairs[base + lane];
        unsigned pk = e.x;
        float v = __uint_as_float(e.y);

        for (int j0 = 0; j0 < rem; j0 += 8) {  // wave-uniform trip count
            unsigned pj[8];
            float vj[8];
            unsigned u[8];
#pragma unroll
            for (int jj = 0; jj < 8; ++jj) {
                pj[jj] = __shfl(pk, j0 + jj);
                vj[jj] = __shfl(v, j0 + jj);
            }
#pragma unroll
            for (int jj = 0; jj < 8; ++jj) {
                int c = (int)(pj[jj] & 0x01FFFFFFu);
                u[jj] = *reinterpret_cast<const unsigned*>(xb + (size_t)c * D + lane * 2);
            }
#pragma unroll
            for (int jj = 0; jj < 8; ++jj) {
                int lr = (int)(pj[jj] >> 25);
                float xlo = __uint_as_float(u[jj] << 16);
                float xhi = __uint_as_float(u[jj] & 0xFFFF0000u);
                atomicAdd(&ylds[lr][lane * 2 + 0], vj[jj] * xlo);
                atomicAdd(&ylds[lr][lane * 2 + 1], vj[jj] * xhi);
            }
        }
    }
    __syncthreads();

    // write tile out as bf16 (coalesced u32 per thread)
    for (int i = tid; i < RPB * (D / 2); i += 512) {
        int r = i >> 6, q = i & 63;
        int grow = row0 + r;
        if (grow < N) {
            unsigned o = (unsigned)f2bf(ylds[r][2 * q]) |
                         ((unsigned)f2bf(ylds[r][2 * q + 1]) << 16);
            *reinterpret_cast<unsigned*>(yb + (size_t)grow * D + 2 * q) = o;
        }
    }
}

// ---------------------------------------------------------------------------
// Projection: out = y * W^T via MFMA bf16 16x16x32 (layouts m89-verified).
// ---------------------------------------------------------------------------
__global__ __launch_bounds__(256) void gemm_mfma(const unsigned short* __restrict__ yb,
                                                 const unsigned short* __restrict__ Wb,
                                                 float* __restrict__ out, int N) {
    const int wid  = threadIdx.x >> 6;
    const int lane = threadIdx.x & 63;
    const int m0   = blockIdx.x * 64 + wid * 16;
    const int r    = lane & 15;
    const int kg   = lane >> 4;  // 0..3
    const int arow = m0 + r;

    f32x4 acc[8] = {};
#pragma unroll
    for (int ks = 0; ks < 4; ++ks) {
        const int k0 = ks * 32 + kg * 8;
        bf16x8 a = {};
        if (arow < N) a = *reinterpret_cast<const bf16x8*>(yb + (size_t)arow * D + k0);
#pragma unroll
        for (int t = 0; t < 8; ++t) {
            bf16x8 b = *reinterpret_cast<const bf16x8*>(Wb + (size_t)(t * 16 + r) * D + k0);
            acc[t] = __builtin_amdgcn_mfma_f32_16x16x32_bf16(a, b, acc[t], 0, 0, 0);
        }
    }
#pragma unroll
    for (int t = 0; t < 8; ++t) {
#pragma unroll
        for (int i = 0; i < 4; ++i) {
            const int row = m0 + kg * 4 + i;
            if (row < N) out[(size_t)row * D + t * 16 + r] = acc[t][i];
        }
    }
}

// ---------------------------------------------------------------------------
// Fallback path (tiny workspace): fp32 VALU GEMM + atomic scatter
// ---------------------------------------------------------------------------
__global__ __launch_bounds__(256) void gemm64(const float* __restrict__ x,
                                              const float* __restrict__ W,
                                              float* __restrict__ h, int N) {
    __shared__ float xs[128][64];
    __shared__ float ws[128][64];
    const int tid = threadIdx.x;
    const int m0 = blockIdx.x * 64;
    const int n0 = blockIdx.y * 64;
    for (int idx = tid; idx < 2048; idx += 256) {
        int q = idx >> 6, m = idx & 63;
        int grow = m0 + m;
        float4 v = make_float4(0.f, 0.f, 0.f, 0.f);
        if (grow < N) v = *reinterpret_cast<const float4*>(x + (size_t)grow * D + q * 4);
        xs[q * 4 + 0][m] = v.x; xs[q * 4 + 1][m] = v.y;
        xs[q * 4 + 2][m] = v.z; xs[q * 4 + 3][m] = v.w;
    }
    for (int idx = tid; idx < 2048; idx += 256) {
        int q = idx >> 6, n = idx & 63;
        float4 v = *reinterpret_cast<const float4*>(W + (size_t)(n0 + n) * D + q * 4);
        ws[q * 4 + 0][n] = v.x; ws[q * 4 + 1][n] = v.y;
        ws[q * 4 + 2][n] = v.z; ws[q * 4 + 3][n] = v.w;
    }
    __syncthreads();
    const int tm = (tid & 15) * 4;
    const int tn = (tid >> 4) * 4;
    float acc[4][4] = {};
#pragma unroll 4
    for (int k = 0; k < 128; ++k) {
        float4 a4 = *reinterpret_cast<const float4*>(&xs[k][tm]);
        float4 b4 = *reinterpret_cast<const float4*>(&ws[k][tn]);
        float a[4] = {a4.x, a4.y, a4.z, a4.w};
        float b[4] = {b4.x, b4.y, b4.z, b4.w};
#pragma unroll
        for (int rr = 0; rr < 4; ++rr)
#pragma unroll
            for (int cc = 0; cc < 4; ++cc) acc[rr][cc] = fmaf(a[rr], b[cc], acc[rr][cc]);
    }
#pragma unroll
    for (int rr = 0; rr < 4; ++rr) {
        int row = m0 + tm + rr;
        if (row < N) {
            float4 o = make_float4(acc[rr][0], acc[rr][1], acc[rr][2], acc[rr][3]);
            *reinterpret_cast<float4*>(h + (size_t)row * D + n0 + tn) = o;
        }
    }
}

__global__ __launch_bounds__(256) void scatter_edges(const float* __restrict__ h,
                                                     const int* __restrict__ rows,
                                                     const int* __restrict__ cols,
                                                     const float* __restrict__ vals,
                                                     float* __restrict__ out, int E) {
    int t = blockIdx.x * 256 + threadIdx.x;
    int e = t >> 5;
    if (e >= E) return;
    int q = t & 31;
    int r = rows[e];
    int c = cols[e];
    float v = vals[e];
    float4 m = reinterpret_cast<const float4*>(h + (size_t)c * D)[q];
    float* op = out + (size_t)r * D + q * 4;
    atomicAdd(op + 0, v * m.x);
    atomicAdd(op + 1, v * m.y);
    atomicAdd(op + 2, v * m.z);
    atomicAdd(op + 3, v * m.w);
}

extern "C" void kernel_launch(void* const* d_in, const int* in_sizes, int n_in,
                              void* d_out, int out_size, void* d_ws, size_t ws_size,
                              hipStream_t stream) {
    const float* x        = (const float*)d_in[0];
    const float* W        = (const float*)d_in[1];
    const int*   adj_rows = (const int*)d_in[2];
    const int*   adj_cols = (const int*)d_in[3];
    const float* adj_vals = (const float*)d_in[4];
    float* out = (float*)d_out;

    const int N = in_sizes[0] / D;
    const int E = in_sizes[2];
    const int NBUCK = (N + RPB - 1) / RPB;
    const int NT = (E + TILE - 1) / TILE;

    // ---- workspace carve (ws) ----
    size_t off = 0;
    auto carve = [&](size_t bytes) {
        void* p = (char*)d_ws + off;
        off += (bytes + 255) & ~(size_t)255;
        return p;
    };
    unsigned short* xb = (unsigned short*)carve((size_t)N * D * 2);  // 25.6 MB
    unsigned short* yb = (unsigned short*)carve((size_t)N * D * 2);  // 25.6 MB
    unsigned short* Wb = (unsigned short*)carve((size_t)D * D * 2);
    int* bucketCnt  = (int*)carve((size_t)BUCKMAX * sizeof(int));
    int* bucketBase = (int*)carve((size_t)(BUCKMAX + 1) * sizeof(int));
    int* bucketCur  = (int*)carve((size_t)BUCKMAX * sizeof(int));
    const size_t wsNeed = off;

    // ---- scratch carved from d_out (dead before gemm_mfma overwrites) ----
    uint2* pairs = (uint2*)d_out;  // E * 8B = 12.8 MB <= 51.2 MB
    const size_t doutNeed = (size_t)E * sizeof(uint2);

    const bool fits = (wsNeed <= ws_size) &&
                      (doutNeed <= (size_t)out_size * sizeof(float)) &&
                      (NBUCK <= BUCKMAX) && (N < (1 << 25));

    if (fits) {
        cast_bf16<<<2048, 256, 0, stream>>>(x, xb, (long long)N * (D / 4));
        cast_bf16<<<16, 256, 0, stream>>>(W, Wb, (long long)D * (D / 4));
        hipMemsetAsync(bucketCnt, 0, (size_t)BUCKMAX * sizeof(int), stream);
        bucket_hist<<<NT, 1024, 0, stream>>>(adj_rows, bucketCnt, E, NBUCK);
        bucket_scan<<<1, 256, 0, stream>>>(bucketCnt, bucketBase, bucketCur, NBUCK);
        binA<<<NT, 1024, 0, stream>>>(adj_rows, adj_cols, adj_vals, bucketBase,
                                      bucketCur, pairs, E, NBUCK);
        bucket_spmm<<<NBUCK, 512, 0, stream>>>(xb, bucketBase, pairs, yb, N);
        gemm_mfma<<<(N + 63) / 64, 256, 0, stream>>>(yb, Wb, out, N);
    } else {
        float* h = (float*)d_ws;
        hipMemsetAsync(d_out, 0, (size_t)out_size * sizeof(float), stream);
        dim3 ggrid((N + 63) / 64, D / 64);
        gemm64<<<ggrid, 256, 0, stream>>>(x, W, h, N);
        const long long tt = (long long)E * 32;
        scatter_edges<<<(int)((tt + 255) / 256), 256, 0, stream>>>(
            h, adj_rows, adj_cols, adj_vals, out, E);
    }
}

// Round 7
// 161.089 us; speedup vs baseline: 9.1019x; 9.1019x over previous
//
#include <hip/hip_runtime.h>

#define D 128          // D_IN == D_OUT == 128
#define RPB 512        // rows per bucket
#define RPB_SHIFT 9
#define HALF 256       // rows handled per csr_build block
#define BUCKMAX 256
#define TILE 8192      // edges per binning tile
#define SEGCAP 7168    // LDS pair capacity per csr_build block (56 KiB)

typedef short bf16x8 __attribute__((ext_vector_type(8)));
typedef float f32x4 __attribute__((ext_vector_type(4)));

__device__ inline unsigned short f2bf(float f) {  // RNE float->bf16
    unsigned u = __float_as_uint(f);
    unsigned r = u + 0x7FFFu + ((u >> 16) & 1u);
    return (unsigned short)(r >> 16);
}

// ---------------------------------------------------------------------------
// fp32 -> bf16 cast, 4 elements/thread, grid-stride
// ---------------------------------------------------------------------------
__global__ __launch_bounds__(256) void cast_bf16(const float* __restrict__ src,
                                                 unsigned short* __restrict__ dst,
                                                 long long n4) {
    long long i = (long long)blockIdx.x * 256 + threadIdx.x;
    const long long stride = (long long)gridDim.x * 256;
    for (; i < n4; i += stride) {
        float4 v = reinterpret_cast<const float4*>(src)[i];
        ushort4 o;
        o.x = f2bf(v.x); o.y = f2bf(v.y); o.z = f2bf(v.z); o.w = f2bf(v.w);
        reinterpret_cast<ushort4*>(dst)[i] = o;
    }
}

// ---------------------------------------------------------------------------
// Pass 0: exact per-bucket edge counts (bucket = row >> RPB_SHIFT)
// 1024 threads for occupancy.
// ---------------------------------------------------------------------------
__global__ __launch_bounds__(1024) void bucket_hist(const int* __restrict__ rows,
                                                    int* __restrict__ bucketCnt,
                                                    int E, int NBUCK) {
    __shared__ int h[BUCKMAX];
    for (int i = threadIdx.x; i < NBUCK; i += 1024) h[i] = 0;
    __syncthreads();
    const int t0 = blockIdx.x * TILE;
    const int tend = min(t0 + TILE, E);
    for (int i = t0 + threadIdx.x; i < tend; i += 1024)
        atomicAdd(&h[rows[i] >> RPB_SHIFT], 1);
    __syncthreads();
    for (int i = threadIdx.x; i < NBUCK; i += 1024)
        if (h[i]) atomicAdd(&bucketCnt[i], h[i]);
}

// ---------------------------------------------------------------------------
// Parallel exclusive scan over NBUCK (<=256) bucket counts; zero cursors.
// ---------------------------------------------------------------------------
__global__ __launch_bounds__(256) void bucket_scan(const int* __restrict__ bucketCnt,
                                                   int* __restrict__ bucketBase,
                                                   int* __restrict__ bucketCur,
                                                   int* __restrict__ offsets,
                                                   int NBUCK, int N) {
    __shared__ int t[256];
    const int tid = threadIdx.x;
    int v = (tid < NBUCK) ? bucketCnt[tid] : 0;
    t[tid] = v;
    __syncthreads();
    for (int ofs = 1; ofs < 256; ofs <<= 1) {
        int add = (tid >= ofs) ? t[tid - ofs] : 0;
        __syncthreads();
        t[tid] += add;
        __syncthreads();
    }
    if (tid < NBUCK) {
        bucketBase[tid] = t[tid] - v;  // exclusive
        bucketCur[tid] = 0;
    }
    if (tid == NBUCK - 1) {
        bucketBase[NBUCK] = t[tid];
        offsets[N] = t[tid];  // == E
    }
}

// ---------------------------------------------------------------------------
// Pass 1: bin edges into bucket-major PACKED pairs: (lrow9<<23 | col, val).
// Per-tile LDS histogram, ONE global atomic reservation per (tile,bucket),
// single-stream uint2 writes into the tile's private contiguous chunk.
// 1024 threads (R5's 6.7%-occupancy bottleneck fix).
// ---------------------------------------------------------------------------
__global__ __launch_bounds__(1024) void binA(const int* __restrict__ rows,
                                             const int* __restrict__ cols,
                                             const float* __restrict__ vals,
                                             const int* __restrict__ bucketBase,
                                             int* __restrict__ bucketCur,
                                             uint2* __restrict__ pairs_bin,
                                             int E, int NBUCK) {
    __shared__ int h[BUCKMAX];
    __shared__ int base[BUCKMAX];
    const int t0 = blockIdx.x * TILE;
    const int tend = min(t0 + TILE, E);
    for (int i = threadIdx.x; i < NBUCK; i += 1024) h[i] = 0;
    __syncthreads();
    for (int i = t0 + threadIdx.x; i < tend; i += 1024)
        atomicAdd(&h[rows[i] >> RPB_SHIFT], 1);
    __syncthreads();
    for (int i = threadIdx.x; i < NBUCK; i += 1024) {
        int c = h[i];
        base[i] = c ? bucketBase[i] + atomicAdd(&bucketCur[i], c) : 0;
        h[i] = 0;  // reuse as local cursor
    }
    __syncthreads();
    for (int i = t0 + threadIdx.x; i < tend; i += 1024) {
        int r = rows[i];
        int b = r >> RPB_SHIFT;
        int p = base[b] + atomicAdd(&h[b], 1);
        unsigned pk = ((unsigned)(r & (RPB - 1)) << 23) | (unsigned)cols[i];
        pairs_bin[p] = make_uint2(pk, __float_as_uint(vals[i]));
    }
}

// ---------------------------------------------------------------------------
// Pass 2: per 256-row half-bucket, build the sorted CSR segment in LDS and
// write it out coalesced; emit per-row global offsets. Overflow (>SEGCAP)
// falls back to direct (correct, slower) global scatter.
// ---------------------------------------------------------------------------
__global__ __launch_bounds__(256) void csr_build(const uint2* __restrict__ pairs_bin,
                                                 const int* __restrict__ bucketBase,
                                                 int* __restrict__ offsets,
                                                 uint2* __restrict__ pairs_g, int N) {
    __shared__ int hist[HALF];
    __shared__ int cur[HALF];
    __shared__ int tsum[256];
    __shared__ uint2 pr[SEGCAP];
    __shared__ int cntBelowSh;
    const int tid = threadIdx.x;
    const int buck = blockIdx.x >> 1, half = blockIdx.x & 1;
    const int lrow0 = half * HALF;          // bucket-local base of this half
    const int grow0 = buck * RPB + lrow0;   // global row base
    const int rbeg = bucketBase[buck], rend = bucketBase[buck + 1];

    hist[tid] = 0;
    if (tid == 0) cntBelowSh = 0;
    __syncthreads();

    int below = 0;
    for (int i = rbeg + tid; i < rend; i += 256) {
        int d = (int)(pairs_bin[i].x >> 23) - lrow0;
        if ((unsigned)d < (unsigned)HALF) atomicAdd(&hist[d], 1);
        else if (d < 0) ++below;
    }
    if (below) atomicAdd(&cntBelowSh, below);
    __syncthreads();

    int part = hist[tid];
    tsum[tid] = part;
    __syncthreads();
    for (int ofs = 1; ofs < 256; ofs <<= 1) {
        int add = (tid >= ofs) ? tsum[tid - ofs] : 0;
        __syncthreads();
        tsum[tid] += add;
        __syncthreads();
    }
    const int excl = tsum[tid] - part;
    const int segcnt = tsum[255];
    const int segbase = rbeg + cntBelowSh;

    cur[tid] = excl;
    const int grow = grow0 + tid;
    if (grow < N) offsets[grow] = segbase + excl;
    __syncthreads();

    if (segcnt <= SEGCAP) {
        for (int i = rbeg + tid; i < rend; i += 256) {
            uint2 e = pairs_bin[i];
            int d = (int)(e.x >> 23) - lrow0;
            if ((unsigned)d < (unsigned)HALF) {
                int p = atomicAdd(&cur[d], 1);
                pr[p] = make_uint2(e.x & 0x7FFFFFu, e.y);
            }
        }
        __syncthreads();
        for (int p = tid; p < segcnt; p += 256) pairs_g[segbase + p] = pr[p];
    } else {
        for (int i = rbeg + tid; i < rend; i += 256) {
            uint2 e = pairs_bin[i];
            int d = (int)(e.x >> 23) - lrow0;
            if ((unsigned)d < (unsigned)HALF) {
                int p = atomicAdd(&cur[d], 1);
                pairs_g[segbase + p] = make_uint2(e.x & 0x7FFFFFu, e.y);
            }
        }
    }
}

// ---------------------------------------------------------------------------
// Aggregation: y[row] = sum val * xb[col]  (bf16 gather, fp32 acc, bf16 out)
// One wave per row. 64 pairs batch-loaded lane-parallel; inner loop is
// BRANCH-FREE groups of 8 {shfl, load, fma}: 8 gathers in flight (R5-proven).
// ---------------------------------------------------------------------------
__global__ __launch_bounds__(256) void csr_gather_bf16(
    const unsigned short* __restrict__ xb,
    const int* __restrict__ offsets,
    const uint2* __restrict__ pairs,
    unsigned short* __restrict__ yb, int N) {
    const int row = blockIdx.x * 4 + (threadIdx.x >> 6);
    if (row >= N) return;
    const int lane = threadIdx.x & 63;
    const int beg = offsets[row], end = offsets[row + 1];
    float ax = 0.f, ay = 0.f;

    for (int base = beg; base < end; base += 64) {
        const int rem = min(end - base, 64);  // wave-uniform
        uint2 e = make_uint2(0u, 0u);         // pad lanes: col 0, val 0
        if (lane < rem) e = pairs[base + lane];
        int c = (int)e.x;
        float v = __uint_as_float(e.y);

        for (int j0 = 0; j0 < rem; j0 += 8) {  // wave-uniform trip count
            int cj[8];
            float vj[8];
            unsigned u[8];
#pragma unroll
            for (int jj = 0; jj < 8; ++jj) {
                cj[jj] = __shfl(c, j0 + jj);
                vj[jj] = __shfl(v, j0 + jj);
            }
#pragma unroll
            for (int jj = 0; jj < 8; ++jj)
                u[jj] = *reinterpret_cast<const unsigned*>(
                    xb + (size_t)cj[jj] * D + lane * 2);
#pragma unroll
            for (int jj = 0; jj < 8; ++jj) {
                ax = fmaf(vj[jj], __uint_as_float(u[jj] << 16), ax);
                ay = fmaf(vj[jj], __uint_as_float(u[jj] & 0xFFFF0000u), ay);
            }
        }
    }
    unsigned o = (unsigned)f2bf(ax) | ((unsigned)f2bf(ay) << 16);
    *reinterpret_cast<unsigned*>(yb + (size_t)row * D + lane * 2) = o;
}

// ---------------------------------------------------------------------------
// Projection: out = y * W^T via MFMA bf16 16x16x32 (layouts m89-verified).
// ---------------------------------------------------------------------------
__global__ __launch_bounds__(256) void gemm_mfma(const unsigned short* __restrict__ yb,
                                                 const unsigned short* __restrict__ Wb,
                                                 float* __restrict__ out, int N) {
    const int wid  = threadIdx.x >> 6;
    const int lane = threadIdx.x & 63;
    const int m0   = blockIdx.x * 64 + wid * 16;
    const int r    = lane & 15;
    const int kg   = lane >> 4;  // 0..3
    const int arow = m0 + r;

    f32x4 acc[8] = {};
#pragma unroll
    for (int ks = 0; ks < 4; ++ks) {
        const int k0 = ks * 32 + kg * 8;
        bf16x8 a = {};
        if (arow < N) a = *reinterpret_cast<const bf16x8*>(yb + (size_t)arow * D + k0);
#pragma unroll
        for (int t = 0; t < 8; ++t) {
            bf16x8 b = *reinterpret_cast<const bf16x8*>(Wb + (size_t)(t * 16 + r) * D + k0);
            acc[t] = __builtin_amdgcn_mfma_f32_16x16x32_bf16(a, b, acc[t], 0, 0, 0);
        }
    }
#pragma unroll
    for (int t = 0; t < 8; ++t) {
#pragma unroll
        for (int i = 0; i < 4; ++i) {
            const int row = m0 + kg * 4 + i;
            if (row < N) out[(size_t)row * D + t * 16 + r] = acc[t][i];
        }
    }
}

// ---------------------------------------------------------------------------
// Fallback path (tiny workspace): fp32 VALU GEMM + atomic scatter
// ---------------------------------------------------------------------------
__global__ __launch_bounds__(256) void gemm64(const float* __restrict__ x,
                                              const float* __restrict__ W,
                                              float* __restrict__ h, int N) {
    __shared__ float xs[128][64];
    __shared__ float ws[128][64];
    const int tid = threadIdx.x;
    const int m0 = blockIdx.x * 64;
    const int n0 = blockIdx.y * 64;
    for (int idx = tid; idx < 2048; idx += 256) {
        int q = idx >> 6, m = idx & 63;
        int grow = m0 + m;
        float4 v = make_float4(0.f, 0.f, 0.f, 0.f);
        if (grow < N) v = *reinterpret_cast<const float4*>(x + (size_t)grow * D + q * 4);
        xs[q * 4 + 0][m] = v.x; xs[q * 4 + 1][m] = v.y;
        xs[q * 4 + 2][m] = v.z; xs[q * 4 + 3][m] = v.w;
    }
    for (int idx = tid; idx < 2048; idx += 256) {
        int q = idx >> 6, n = idx & 63;
        float4 v = *reinterpret_cast<const float4*>(W + (size_t)(n0 + n) * D + q * 4);
        ws[q * 4 + 0][n] = v.x; ws[q * 4 + 1][n] = v.y;
        ws[q * 4 + 2][n] = v.z; ws[q * 4 + 3][n] = v.w;
    }
    __syncthreads();
    const int tm = (tid & 15) * 4;
    const int tn = (tid >> 4) * 4;
    float acc[4][4] = {};
#pragma unroll 4
    for (int k = 0; k < 128; ++k) {
        float4 a4 = *reinterpret_cast<const float4*>(&xs[k][tm]);
        float4 b4 = *reinterpret_cast<const float4*>(&ws[k][tn]);
        float a[4] = {a4.x, a4.y, a4.z, a4.w};
        float b[4] = {b4.x, b4.y, b4.z, b4.w};
#pragma unroll
        for (int rr = 0; rr < 4; ++rr)
#pragma unroll
            for (int cc = 0; cc < 4; ++cc) acc[rr][cc] = fmaf(a[rr], b[cc], acc[rr][cc]);
    }
#pragma unroll
    for (int rr = 0; rr < 4; ++rr) {
        int row = m0 + tm + rr;
        if (row < N) {
            float4 o = make_float4(acc[rr][0], acc[rr][1], acc[rr][2], acc[rr][3]);
            *reinterpret_cast<float4*>(h + (size_t)row * D + n0 + tn) = o;
        }
    }
}

__global__ __launch_bounds__(256) void scatter_edges(const float* __restrict__ h,
                                                     const int* __restrict__ rows,
                                                     const int* __restrict__ cols,
                                                     const float* __restrict__ vals,
                                                     float* __restrict__ out, int E) {
    int t = blockIdx.x * 256 + threadIdx.x;
    int e = t >> 5;
    if (e >= E) return;
    int q = t & 31;
    int r = rows[e];
    int c = cols[e];
    float v = vals[e];
    float4 m = reinterpret_cast<const float4*>(h + (size_t)c * D)[q];
    float* op = out + (size_t)r * D + q * 4;
    atomicAdd(op + 0, v * m.x);
    atomicAdd(op + 1, v * m.y);
    atomicAdd(op + 2, v * m.z);
    atomicAdd(op + 3, v * m.w);
}

extern "C" void kernel_launch(void* const* d_in, const int* in_sizes, int n_in,
                              void* d_out, int out_size, void* d_ws, size_t ws_size,
                              hipStream_t stream) {
    const float* x        = (const float*)d_in[0];
    const float* W        = (const float*)d_in[1];
    const int*   adj_rows = (const int*)d_in[2];
    const int*   adj_cols = (const int*)d_in[3];
    const float* adj_vals = (const float*)d_in[4];
    float* out = (float*)d_out;

    const int N = in_sizes[0] / D;
    const int E = in_sizes[2];
    const int NBUCK = (N + RPB - 1) / RPB;
    const int NT = (E + TILE - 1) / TILE;

    // ---- workspace carve (ws) ----
    size_t off = 0;
    auto carve = [&](size_t bytes) {
        void* p = (char*)d_ws + off;
        off += (bytes + 255) & ~(size_t)255;
        return p;
    };
    unsigned short* xb = (unsigned short*)carve((size_t)N * D * 2);  // 25.6 MB
    unsigned short* yb = (unsigned short*)carve((size_t)N * D * 2);  // 25.6 MB
    unsigned short* Wb = (unsigned short*)carve((size_t)D * D * 2);
    int* offsets    = (int*)carve((size_t)(N + 1) * sizeof(int));
    int* bucketCnt  = (int*)carve((size_t)BUCKMAX * sizeof(int));
    int* bucketBase = (int*)carve((size_t)(BUCKMAX + 1) * sizeof(int));
    int* bucketCur  = (int*)carve((size_t)BUCKMAX * sizeof(int));
    const size_t wsNeed = off;

    // ---- scratch carved from d_out (dead before gemm_mfma overwrites) ----
    size_t doff = 0;
    auto carveOut = [&](size_t bytes) {
        void* p = (char*)d_out + doff;
        doff += (bytes + 255) & ~(size_t)255;
        return p;
    };
    uint2* pairs_bin = (uint2*)carveOut((size_t)E * sizeof(uint2));  // 12.8 MB
    uint2* pairs_g   = (uint2*)carveOut((size_t)E * sizeof(uint2));  // 12.8 MB
    const size_t doutNeed = doff;

    const bool fits = (wsNeed <= ws_size) &&
                      (doutNeed <= (size_t)out_size * sizeof(float)) &&
                      (NBUCK <= BUCKMAX) && (N < (1 << 23));

    if (fits) {
        cast_bf16<<<2048, 256, 0, stream>>>(x, xb, (long long)N * (D / 4));
        cast_bf16<<<16, 256, 0, stream>>>(W, Wb, (long long)D * (D / 4));
        hipMemsetAsync(bucketCnt, 0, (size_t)BUCKMAX * sizeof(int), stream);
        bucket_hist<<<NT, 1024, 0, stream>>>(adj_rows, bucketCnt, E, NBUCK);
        bucket_scan<<<1, 256, 0, stream>>>(bucketCnt, bucketBase, bucketCur,
                                           offsets, NBUCK, N);
        binA<<<NT, 1024, 0, stream>>>(adj_rows, adj_cols, adj_vals, bucketBase,
                                      bucketCur, pairs_bin, E, NBUCK);
        csr_build<<<NBUCK * 2, 256, 0, stream>>>(pairs_bin, bucketBase,
                                                 offsets, pairs_g, N);
        csr_gather_bf16<<<(N + 3) / 4, 256, 0, stream>>>(xb, offsets, pairs_g, yb, N);
        gemm_mfma<<<(N + 63) / 64, 256, 0, stream>>>(yb, Wb, out, N);
    } else {
        float* h = (float*)d_ws;
        hipMemsetAsync(d_out, 0, (size_t)out_size * sizeof(float), stream);
        dim3 ggrid((N + 63) / 64, D / 64);
        gemm64<<<ggrid, 256, 0, stream>>>(x, W, h, N);
        const long long tt = (long long)E * 32;
        scatter_edges<<<(int)((tt + 255) / 256), 256, 0, stream>>>(
            h, adj_rows, adj_cols, adj_vals, out, E);
    }
}